// Round 2
// baseline (1262.016 us; speedup 1.0000x reference)
//
#include <hip/hip_runtime.h>
#include <math.h>

// Problem constants (reference: N=16384, D=8, S=8192, diag fill 5.0)
#define NFULL 16384
#define SN 8192
#define DIM 8
#define DIAG_FILL 5.0f

// Workspace layout (bytes):
//   [0,4)            acc (float, zeroed by memset together with hist)
//   [256, 256+64K)   hist[16384] (zeroed by memset)
//   [65792, +32K)    csort[8192]
//   [98560, +32K)    sqg[8192]
//   [131328, +256K)  zg[8192*8]  (16B-aligned)
#define OFF_ACC   0
#define OFF_HIST  256
#define OFF_CSORT (OFF_HIST + NFULL * 4)
#define OFF_SQG   (OFF_CSORT + SN * 4)
#define OFF_ZG    (OFF_SQG + SN * 4)

// One block, 1024 threads: histogram (global atomics on pre-zeroed hist) ->
// exclusive scan (LDS) -> counting-sort emit (LDS + global csort) ->
// gather z rows + squared norms in sorted order.
__global__ __launch_bounds__(1024) void prep_kernel(
    const float* __restrict__ latent_z, const int* __restrict__ sample_idx,
    int* __restrict__ hist, int* __restrict__ csort,
    float* __restrict__ zg, float* __restrict__ sqg, float* __restrict__ acc) {
    __shared__ int partial[1024];   // 4 KB
    __shared__ int csl[SN];         // 32 KB
    int t = threadIdx.x;

    // 1) histogram: 8 samples per thread
    #pragma unroll
    for (int k = 0; k < 8; k++) atomicAdd(&hist[sample_idx[k * 1024 + t]], 1);
    __syncthreads();   // barrier drains vmcnt -> atomics committed at L2

    // 2) per-thread serial scan over 16 bins (atomic loads bypass L1 -> see L2 truth)
    int base = t * 16;
    int cnt[16], loc[16], s = 0;
    #pragma unroll
    for (int k = 0; k < 16; k++) {
        cnt[k] = __hip_atomic_load(&hist[base + k], __ATOMIC_RELAXED, __HIP_MEMORY_SCOPE_AGENT);
        loc[k] = s; s += cnt[k];
    }
    // block-wide inclusive scan of per-thread sums
    int val = s;
    partial[t] = val;
    __syncthreads();
    for (int off = 1; off < 1024; off <<= 1) {
        int add = (t >= off) ? partial[t - off] : 0;
        __syncthreads();
        val += add;
        partial[t] = val;
        __syncthreads();
    }
    int excl = val - s;

    // 3) counting-sort emit (to LDS for step 4, and to global for main_kernel)
    #pragma unroll
    for (int k = 0; k < 16; k++) {
        int st = excl + loc[k];
        for (int c = 0; c < cnt[k]; c++) { csl[st + c] = base + k; csort[st + c] = base + k; }
    }
    __syncthreads();

    // 4) gather z rows (sorted order) + squared norms
    #pragma unroll
    for (int k = 0; k < 8; k++) {
        int a = k * 1024 + t;
        int r = csl[a];
        const float4* src = (const float4*)(latent_z + (size_t)r * DIM);
        float4 u = src[0], v = src[1];
        float4* dst = (float4*)(zg + (size_t)a * DIM);
        dst[0] = u; dst[1] = v;
        sqg[a] = u.x*u.x + u.y*u.y + u.z*u.z + u.w*u.w
               + v.x*v.x + v.y*v.y + v.z*v.z + v.w*v.w;
    }
    if (t == 0) acc[0] = 0.f;   // redundant with memset; harmless
}

// Main: 2048 blocks x 256 threads. Block = (j-group of 256 sorted columns) x
// (i-chunk of 128 sorted rows). Lane owns column j (z_j, c_j in registers).
// The i-chunk's row data (z, sq, r<<14) is staged in LDS once; the inner loop
// is then 1 windowed rel gather + broadcast LDS reads + ~20 VALU per pair.
__global__ __launch_bounds__(256) void
main_kernel(const float* __restrict__ relation, const int* __restrict__ csort,
            const float* __restrict__ zg, const float* __restrict__ sqg,
            float* __restrict__ acc) {
    __shared__ float zs[128 * 8];   // 4 KB
    __shared__ float sqs[128];
    __shared__ int   ro[128];       // r << 14 (rel row offset, fits in 28 bits)

    int jg = blockIdx.x & 31;    // 32 j-groups of 256 columns
    int ic = blockIdx.x >> 5;    // 64 i-chunks of 128 rows
    int t = threadIdx.x;
    int j = jg * 256 + t;

    int cj = csort[j];
    const float4* zj4 = (const float4*)(zg + (size_t)j * DIM);
    float4 p = zj4[0], q = zj4[1];
    float sqj = sqg[j];

    if (t < 128) {
        int a = ic * 128 + t;
        int r = csort[a];
        ro[t] = r << 14;
        const float4* za4 = (const float4*)(zg + (size_t)a * DIM);
        ((float4*)(zs + t * 8))[0] = za4[0];
        ((float4*)(zs + t * 8))[1] = za4[1];
        sqs[t] = sqg[a];
    }
    __syncthreads();

    int kd = j - ic * 128;   // k of the diagonal element, if within this chunk
    float sum = 0.f;
    #pragma unroll 8
    for (int k = 0; k < 128; k++) {
        float rel = relation[(size_t)(unsigned)(ro[k] + cj)];   // windowed gather
        const float4* zk = (const float4*)(zs + k * 8);
        float4 u = zk[0], v = zk[1];
        float sqa = sqs[k];
        float dot = u.x*p.x + u.y*p.y + u.z*p.z + u.w*p.w
                  + v.x*q.x + v.y*q.y + v.z*q.z + v.w*q.w;
        float d2 = fmaxf(sqa + sqj - 2.f * dot, 0.f);
        float dist = sqrtf(d2);
        float den = rel;
        if (k == kd) { dist = 0.f; den = DIAG_FILL; }   // sorted diag == orig diag
        float d = dist - rel;
        sum += d * d * __builtin_amdgcn_rcpf(den);
    }

    // Reduce 256 threads -> 1 atomicAdd
    #pragma unroll
    for (int o = 32; o > 0; o >>= 1) sum += __shfl_down(sum, o, 64);
    __shared__ float part[4];
    int lane = t & 63, w = t >> 6;
    if (lane == 0) part[w] = sum;
    __syncthreads();
    if (t == 0) atomicAdd(acc, part[0] + part[1] + part[2] + part[3]);
}

__global__ void final_kernel(const float* __restrict__ acc, float* __restrict__ out) {
    out[0] = sqrtf(acc[0]);
}

extern "C" void kernel_launch(void* const* d_in, const int* in_sizes, int n_in,
                              void* d_out, int out_size, void* d_ws, size_t ws_size,
                              hipStream_t stream) {
    const float* latent_z   = (const float*)d_in[0];  // [16384, 8]
    const float* relation   = (const float*)d_in[1];  // [16384, 16384]
    const int*   sample_idx = (const int*)d_in[2];    // [8192]
    float* out = (float*)d_out;

    char* ws = (char*)d_ws;
    float* acc  = (float*)(ws + OFF_ACC);
    int*  hist  = (int*)(ws + OFF_HIST);
    int*  csort = (int*)(ws + OFF_CSORT);
    float* sqg  = (float*)(ws + OFF_SQG);
    float* zg   = (float*)(ws + OFF_ZG);

    // zero acc + hist (ws is poisoned 0xAA before every timed launch)
    hipMemsetAsync(d_ws, 0, OFF_HIST + NFULL * 4, stream);

    prep_kernel<<<1, 1024, 0, stream>>>(latent_z, sample_idx, hist, csort, zg, sqg, acc);
    main_kernel<<<2048, 256, 0, stream>>>(relation, csort, zg, sqg, acc);
    final_kernel<<<1, 1, 0, stream>>>(acc, out);
}